// Round 10
// baseline (236.290 us; speedup 1.0000x reference)
//
#include <hip/hip_runtime.h>
#include <stdint.h>

#define ROWLEN 4096
#define KSEL   1024
#define NTHREADS 256
#define NBINS  4096      // 12-bit digit = v >> 20
#define KEYCAP 1536
#define GLCAP  64        // >64 active groups -> fallback (never for N(0,1))
#define JOBCAP 64
typedef unsigned long long u64;

// Monotonic float->uint map: order(f) preserved as unsigned compare.
__device__ __forceinline__ uint32_t f2u_sortable(float f) {
    uint32_t u = __float_as_uint(f);
    return u ^ ((int32_t)u < 0 ? 0xFFFFFFFFu : 0x80000000u);
}

// One bitonic exchange via lane shuffle at segment width W; i = index within segment.
template<int W>
__device__ __forceinline__ uint32_t shstW(uint32_t r, int i, int j, int k) {
    uint32_t o = __shfl_xor(r, j, W);
    bool takeMax = (((i & j) == 0) == ((i & k) == 0));
    return ((r > o) == takeMax) ? r : o;   // keys distinct within a group
}
__device__ __forceinline__ void cmpex32(uint32_t &a, uint32_t &b, bool maxFirst) {
    uint32_t lo = a < b ? a : b, hi = a < b ? b : a;
    a = maxFirst ? hi : lo;
    b = maxFirst ? lo : hi;
}

// Descending bitonic sorts, named scalars only (no arrays -> no scratch risk).
// sort16d: 4 independent 16-lane segments per wave. sort32d: 2 segments.
__device__ __forceinline__ void sort16d(uint32_t &r0, int subl) {
#pragma unroll
    for (int k = 2; k <= 16; k <<= 1)
#pragma unroll
        for (int j = k >> 1; j > 0; j >>= 1)
            r0 = shstW<16>(r0, subl, j, k);
}
__device__ __forceinline__ void sort32d(uint32_t &r0, int subl) {
#pragma unroll
    for (int k = 2; k <= 32; k <<= 1)
#pragma unroll
        for (int j = k >> 1; j > 0; j >>= 1)
            r0 = shstW<32>(r0, subl, j, k);
}
__device__ __forceinline__ void sort64d(uint32_t &r0, int lane) {
#pragma unroll
    for (int k = 2; k <= 64; k <<= 1)
#pragma unroll
        for (int j = k >> 1; j > 0; j >>= 1)
            r0 = shstW<64>(r0, lane, j, k);
}
__device__ __forceinline__ void sort128d(uint32_t &r0, uint32_t &r1, int lane) {
    const int i0 = lane, i1 = lane + 64;
#pragma unroll
    for (int k = 2; k <= 64; k <<= 1)
#pragma unroll
        for (int j = k >> 1; j > 0; j >>= 1) {
            r0 = shstW<64>(r0, i0, j, k);
            r1 = shstW<64>(r1, i1, j, k);
        }
    cmpex32(r0, r1, true);                 // k=128, j=64
#pragma unroll
    for (int j = 32; j > 0; j >>= 1) {
        r0 = shstW<64>(r0, i0, j, 128);
        r1 = shstW<64>(r1, i1, j, 128);
    }
}
__device__ __forceinline__ void sort256d(uint32_t &r0, uint32_t &r1,
                                         uint32_t &r2, uint32_t &r3, int lane) {
    const int i0 = lane, i1 = lane + 64, i2 = lane + 128, i3 = lane + 192;
#pragma unroll
    for (int k = 2; k <= 64; k <<= 1)
#pragma unroll
        for (int j = k >> 1; j > 0; j >>= 1) {
            r0 = shstW<64>(r0, i0, j, k);
            r1 = shstW<64>(r1, i1, j, k);
            r2 = shstW<64>(r2, i2, j, k);
            r3 = shstW<64>(r3, i3, j, k);
        }
    cmpex32(r0, r1, true);                 // k=128, j=64
    cmpex32(r2, r3, false);
#pragma unroll
    for (int j = 32; j > 0; j >>= 1) {
        r0 = shstW<64>(r0, i0, j, 128);
        r1 = shstW<64>(r1, i1, j, 128);
        r2 = shstW<64>(r2, i2, j, 128);
        r3 = shstW<64>(r3, i3, j, 128);
    }
    cmpex32(r0, r2, true); cmpex32(r1, r3, true);   // k=256, j=128
    cmpex32(r0, r1, true); cmpex32(r2, r3, true);   // k=256, j=64
#pragma unroll
    for (int j = 32; j > 0; j >>= 1) {
        r0 = shstW<64>(r0, i0, j, 256);
        r1 = shstW<64>(r1, i1, j, 256);
        r2 = shstW<64>(r2, i2, j, 256);
        r3 = shstW<64>(r3, i3, j, 256);
    }
}

__global__ __launch_bounds__(NTHREADS, 8) void adaptive_topk_kernel(
    const float* __restrict__ in, int* __restrict__ out_idx, int* __restrict__ out_k)
{
    __shared__ uint32_t A32[NBINS / 2];   // 8 KB packed u16 bins: hist -> bases/cursors
    __shared__ uint32_t keys[KEYCAP];     // 6 KB u32 group-scatter keys
    __shared__ uint16_t outbuf[KSEL];     // 2 KB sorted indices staging
    __shared__ uint32_t glist[GLCAP];     // (n<<16)|base per active group
    __shared__ uint32_t jlist[4 * JOBCAP];// 4 slot entries per job
    __shared__ uint32_t jtypes[JOBCAP];   // 0=S(4x16) 1=M(2x32) 2=L64 3=XL128 4=XXL256
    __shared__ uint32_t wavetot[4];
    __shared__ float wsum[4], wsum2[4];
    __shared__ int sh_d1, sh_ng, sh_gp, sh_fb, sh_nj;

    const int row  = blockIdx.x;
    const int tid  = threadIdx.x;
    const int lane = tid & 63;
    const int wv   = tid >> 6;
    const float* __restrict__ rowp = in + (size_t)row * ROWLEN;
    int* __restrict__ orow = out_idx + (size_t)row * KSEL;
    const float4* r4 = (const float4*)rowp;

    const uint4 z0 = {0u, 0u, 0u, 0u};
    ((uint4*)A32)[tid] = z0;              // clear 2048 words (4096 u16 bins)
    ((uint4*)A32)[tid + 256] = z0;
    if (tid == 0) { sh_ng = 0; sh_gp = 0; sh_fb = 0; }
    __syncthreads();

    // ---- pass 1 over input: 12-bit histogram (packed u16) + moments.
    //      Values NOT kept in registers (scratch hazard) - re-read later (cache-hot).
    float s = 0.0f, s2 = 0.0f;
#pragma unroll
    for (int it = 0; it < 4; ++it) {
        float4 v = r4[tid + 256 * it];
        s += (v.x + v.y) + (v.z + v.w);
        s2 = fmaf(v.x, v.x, fmaf(v.y, v.y, fmaf(v.z, v.z, fmaf(v.w, v.w, s2))));
        uint32_t bx = f2u_sortable(v.x) >> 20, by = f2u_sortable(v.y) >> 20;
        uint32_t bz = f2u_sortable(v.z) >> 20, bw = f2u_sortable(v.w) >> 20;
        atomicAdd(&A32[bx >> 1], (bx & 1) ? (1u << 16) : 1u);
        atomicAdd(&A32[by >> 1], (by & 1) ? (1u << 16) : 1u);
        atomicAdd(&A32[bz >> 1], (bz & 1) ? (1u << 16) : 1u);
        atomicAdd(&A32[bw >> 1], (bw & 1) ? (1u << 16) : 1u);
    }
    for (int off = 32; off > 0; off >>= 1) {
        s  += __shfl_down(s, off);
        s2 += __shfl_down(s2, off);
    }
    if (lane == 0) { wsum[wv] = s; wsum2[wv] = s2; }
    __syncthreads();                      // hist + wsum complete
    if (tid == 0) {
        double S  = (double)wsum[0] + wsum[1] + wsum[2] + wsum[3];
        double S2 = (double)wsum2[0] + wsum2[1] + wsum2[2] + wsum2[3];
        double var = (S2 - S * S / (double)ROWLEN) / (double)(ROWLEN - 1);
        float sp = log1pf(expf((float)var));
        float ka = 512.0f * (1.0f + 0.1f * sp);
        ka = fminf(fmaxf(ka, 128.0f), 1024.0f);
        out_k[row] = (int)ka;
    }

    // ---- suffix scan over 4096 bins; boundary digit d1; bases into A32 ----
    uint32_t hww[8];                       // my 16 bins, packed (static-indexed)
    {
        uint4 h0 = ((uint4*)A32)[2 * tid];
        uint4 h1 = ((uint4*)A32)[2 * tid + 1];
        hww[0] = h0.x; hww[1] = h0.y; hww[2] = h0.z; hww[3] = h0.w;
        hww[4] = h1.x; hww[5] = h1.y; hww[6] = h1.z; hww[7] = h1.w;
    }
    uint32_t csum = 0;
#pragma unroll
    for (int q = 0; q < 8; ++q) csum += (hww[q] & 0xFFFFu) + (hww[q] >> 16);
    uint32_t incl = csum;                 // inclusive suffix over chunk sums in wave
#pragma unroll
    for (int off = 1; off < 64; off <<= 1) {
        uint32_t t = __shfl_down(incl, off);
        if (lane + off < 64) incl += t;
    }
    if (lane == 0) wavetot[wv] = incl;
    __syncthreads();
    uint32_t later = 0;
    for (int w2 = wv + 1; w2 < 4; ++w2) later += wavetot[w2];
    const uint32_t R = (incl - csum) + later;   // elems in bins after my chunk
    {
        uint32_t run = R;
#pragma unroll
        for (int q = 7; q >= 0; --q) {
            uint32_t h_hi = hww[q] >> 16, h_lo = hww[q] & 0xFFFFu;
            uint32_t base_hi = run;
            if (run < KSEL && KSEL <= run + h_hi) sh_d1 = 16 * tid + 2 * q + 1;
            run += h_hi;
            uint32_t base_lo = run;
            if (run < KSEL && KSEL <= run + h_lo) sh_d1 = 16 * tid + 2 * q;
            run += h_lo;
            A32[8 * tid + q] = (base_hi << 16) | base_lo;
        }
    }
    __syncthreads();                      // bases + sh_d1 visible

    const int d1 = sh_d1;

    // ---- group list build (bases by running subtraction; no arrays) ----
    {
        uint32_t run2 = R + csum;
#pragma unroll
        for (int b = 0; b < 16; ++b) {
            uint32_t n = (hww[b >> 1] >> ((b & 1) * 16)) & 0xFFFFu;
            run2 -= n;                    // = base of bin g
            int g = 16 * tid + b;
            if (g >= d1 && n > 0) {
                if (n > 256) sh_fb = 1;
                int p = atomicAdd(&sh_ng, 1);
                if (p < GLCAP) glist[p] = (n << 16) | run2;
            }
        }
    }
    // ---- pass 2 over input (cache-hot re-read): grouped scatter, u32 keys ----
#pragma unroll
    for (int it = 0; it < 4; ++it) {
        float4 v = r4[tid + 256 * it];
        const int idx0 = 4 * (tid + 256 * it);
#pragma unroll
        for (int e = 0; e < 4; ++e) {
            float f = (e == 0) ? v.x : (e == 1) ? v.y : (e == 2) ? v.z : v.w;
            uint32_t u = f2u_sortable(f);
            int g = (int)(u >> 20);
            if (g >= d1) {
                uint32_t old = atomicAdd(&A32[g >> 1], (g & 1) ? (1u << 16) : 1u);
                uint32_t pos = (g & 1) ? (old >> 16) : (old & 0xFFFFu);
                if (pos < KEYCAP)
                    keys[pos] = (u << 12) | (uint32_t)(ROWLEN - 1 - (idx0 + e));
            }
        }
    }
    __syncthreads();                      // keys + glist complete

    // ---- serial job packer (tid 0): classify groups, pack small ones into
    //      multi-slot sub-width jobs. Groups sort independently (no cross-
    //      group key compares - truncated keys only order within a group).
    if (tid == 0) {
        int ng0 = sh_ng;
        if (ng0 > GLCAP) { sh_fb = 1; sh_nj = 0; }
        else {
            int nj = 0, sJob = -1, sSlot = 0, mJob = -1, mSlot = 0;
            for (int i = 0; i < ng0; ++i) {
                uint32_t e = glist[i];
                uint32_t n = e >> 16;
                if (n <= 16) {
                    if (sJob < 0) {
                        sJob = nj++; jtypes[sJob] = 0; sSlot = 0;
                        jlist[4 * sJob] = 0; jlist[4 * sJob + 1] = 0;
                        jlist[4 * sJob + 2] = 0; jlist[4 * sJob + 3] = 0;
                    }
                    jlist[4 * sJob + sSlot] = e;
                    if (++sSlot == 4) sJob = -1;
                } else if (n <= 32) {
                    if (mJob < 0) {
                        mJob = nj++; jtypes[mJob] = 1; mSlot = 0;
                        jlist[4 * mJob] = 0; jlist[4 * mJob + 1] = 0;
                    }
                    jlist[4 * mJob + mSlot] = e;
                    if (++mSlot == 2) mJob = -1;
                } else {
                    jtypes[nj] = (n <= 64) ? 2u : (n <= 128) ? 3u : 4u;
                    jlist[4 * nj] = e;
                    ++nj;
                }
            }
            sh_nj = nj;
        }
    }
    __syncthreads();                      // jobs + final sh_fb visible

    if (!sh_fb) {
        // ---- per-job in-wave sorts -> LDS outbuf (no barriers) ----
        const int nj = sh_nj;
        for (;;) {
            int j = 0;
            if (lane == 0) j = atomicAdd(&sh_gp, 1);
            j = __shfl(j, 0);
            if (j >= nj) break;
            uint32_t ty = jtypes[j];
            if (ty == 0) {                 // 4 groups x width-16
                int slot = lane >> 4, subl = lane & 15;
                uint32_t e = jlist[4 * j + slot];
                int n = (int)(e >> 16), base = (int)(e & 0xFFFFu);
                uint32_t r0 = (subl < n) ? keys[base + subl] : 0u;
                sort16d(r0, subl);
                int quota = min(n, KSEL - base);
                if (subl < quota)
                    outbuf[base + subl] = (uint16_t)((ROWLEN - 1) - (int)(r0 & 0xFFFu));
            } else if (ty == 1) {          // 2 groups x width-32
                int slot = lane >> 5, subl = lane & 31;
                uint32_t e = jlist[4 * j + slot];
                int n = (int)(e >> 16), base = (int)(e & 0xFFFFu);
                uint32_t r0 = (subl < n) ? keys[base + subl] : 0u;
                sort32d(r0, subl);
                int quota = min(n, KSEL - base);
                if (subl < quota)
                    outbuf[base + subl] = (uint16_t)((ROWLEN - 1) - (int)(r0 & 0xFFFu));
            } else {
                uint32_t e = jlist[4 * j];
                int n = (int)(e >> 16), base = (int)(e & 0xFFFFu);
                int quota = min(n, KSEL - base);
                const int i0 = lane, i1 = lane + 64, i2 = lane + 128, i3 = lane + 192;
                if (ty == 2) {
                    uint32_t r0 = (i0 < n) ? keys[base + i0] : 0u;
                    sort64d(r0, lane);
                    if (i0 < quota)
                        outbuf[base + i0] = (uint16_t)((ROWLEN - 1) - (int)(r0 & 0xFFFu));
                } else if (ty == 3) {
                    uint32_t r0 = (i0 < n) ? keys[base + i0] : 0u;
                    uint32_t r1 = (i1 < n) ? keys[base + i1] : 0u;
                    sort128d(r0, r1, lane);
                    if (i0 < quota)
                        outbuf[base + i0] = (uint16_t)((ROWLEN - 1) - (int)(r0 & 0xFFFu));
                    if (i1 < quota)
                        outbuf[base + i1] = (uint16_t)((ROWLEN - 1) - (int)(r1 & 0xFFFu));
                } else {
                    uint32_t r0 = (i0 < n) ? keys[base + i0] : 0u;
                    uint32_t r1 = (i1 < n) ? keys[base + i1] : 0u;
                    uint32_t r2 = (i2 < n) ? keys[base + i2] : 0u;
                    uint32_t r3 = (i3 < n) ? keys[base + i3] : 0u;
                    sort256d(r0, r1, r2, r3, lane);
                    if (i0 < quota)
                        outbuf[base + i0] = (uint16_t)((ROWLEN - 1) - (int)(r0 & 0xFFFu));
                    if (i1 < quota)
                        outbuf[base + i1] = (uint16_t)((ROWLEN - 1) - (int)(r1 & 0xFFFu));
                    if (i2 < quota)
                        outbuf[base + i2] = (uint16_t)((ROWLEN - 1) - (int)(r2 & 0xFFFu));
                    if (i3 < quota)
                        outbuf[base + i3] = (uint16_t)((ROWLEN - 1) - (int)(r3 & 0xFFFu));
                }
            }
        }
        __syncthreads();                  // outbuf complete
        // ---- single coalesced row store: ushort4 (LDS) -> int4 (global) ----
        ushort4 t4 = ((const ushort4*)outbuf)[tid];
        int4 ov = { (int)t4.x, (int)t4.y, (int)t4.z, (int)t4.w };
        ((int4*)orow)[tid] = ov;
    } else {
        // ---- exact cooperative fallback (statistically never taken) ----
        if (tid < 64) {
            u64 prev = ~0ull;
            for (int r = 0; r < KSEL; ++r) {
                u64 best = 0;
                for (int c = lane; c < ROWLEN; c += 64) {
                    u64 K = ((u64)f2u_sortable(rowp[c]) << 12) | (u64)(ROWLEN - 1 - c);
                    if (K < prev && K > best) best = K;
                }
                for (int off = 32; off > 0; off >>= 1) {
                    u64 o = __shfl_xor(best, off, 64);
                    best = best > o ? best : o;
                }
                if (lane == 0) orow[r] = (ROWLEN - 1) - (int)(best & 0xFFFu);
                prev = best;
            }
        }
    }
}

extern "C" void kernel_launch(void* const* d_in, const int* in_sizes, int n_in,
                              void* d_out, int out_size, void* d_ws, size_t ws_size,
                              hipStream_t stream) {
    const float* in = (const float*)d_in[0];
    const int B = in_sizes[0] / (ROWLEN * ROWLEN);   // 4
    const int nrows = B * ROWLEN;                    // 16384
    int* out = (int*)d_out;
    int* out_idx = out;                              // B*L*KSEL
    int* out_k   = out + (size_t)nrows * KSEL;       // B*L
    adaptive_topk_kernel<<<dim3(nrows), dim3(NTHREADS), 0, stream>>>(in, out_idx, out_k);
}

// Round 11
// 218.051 us; speedup vs baseline: 1.0836x; 1.0836x over previous
//
#include <hip/hip_runtime.h>
#include <stdint.h>

#define ROWLEN 4096
#define KSEL   1024
#define NTHREADS 256
#define NBINS  4096      // 12-bit digit = v >> 20
#define KEYCAP 1536
#define GLCAP  64        // >64 active groups -> fallback (never for N(0,1))
#define JOBCAP 64
typedef unsigned long long u64;

// Monotonic float->uint map: order(f) preserved as unsigned compare.
__device__ __forceinline__ uint32_t f2u_sortable(float f) {
    uint32_t u = __float_as_uint(f);
    return u ^ ((int32_t)u < 0 ? 0xFFFFFFFFu : 0x80000000u);
}

// A32 bank swizzle: involution on word index, preserves 4-word blocks.
// Spreads stride-8 word accesses (scan b128s, base writes) across banks.
__device__ __forceinline__ int aswz(int w) { return w ^ ((w >> 3) & 0x1C); }
__device__ __forceinline__ int swb(int B) { return B ^ ((B >> 3) & 7); }   // block form

// One bitonic exchange via lane shuffle at segment width W; i = index within segment.
template<int W>
__device__ __forceinline__ uint32_t shstW(uint32_t r, int i, int j, int k) {
    uint32_t o = __shfl_xor(r, j, W);
    bool takeMax = (((i & j) == 0) == ((i & k) == 0));
    return ((r > o) == takeMax) ? r : o;   // keys distinct within a group
}
__device__ __forceinline__ void cmpex32(uint32_t &a, uint32_t &b, bool maxFirst) {
    uint32_t lo = a < b ? a : b, hi = a < b ? b : a;
    a = maxFirst ? hi : lo;
    b = maxFirst ? lo : hi;
}

// Descending bitonic sorts, named scalars only (no arrays -> no scratch risk).
__device__ __forceinline__ void sort16d(uint32_t &r0, int subl) {
#pragma unroll
    for (int k = 2; k <= 16; k <<= 1)
#pragma unroll
        for (int j = k >> 1; j > 0; j >>= 1)
            r0 = shstW<16>(r0, subl, j, k);
}
__device__ __forceinline__ void sort32d(uint32_t &r0, int subl) {
#pragma unroll
    for (int k = 2; k <= 32; k <<= 1)
#pragma unroll
        for (int j = k >> 1; j > 0; j >>= 1)
            r0 = shstW<32>(r0, subl, j, k);
}
__device__ __forceinline__ void sort64d(uint32_t &r0, int lane) {
#pragma unroll
    for (int k = 2; k <= 64; k <<= 1)
#pragma unroll
        for (int j = k >> 1; j > 0; j >>= 1)
            r0 = shstW<64>(r0, lane, j, k);
}
__device__ __forceinline__ void sort128d(uint32_t &r0, uint32_t &r1, int lane) {
    const int i0 = lane, i1 = lane + 64;
#pragma unroll
    for (int k = 2; k <= 64; k <<= 1)
#pragma unroll
        for (int j = k >> 1; j > 0; j >>= 1) {
            r0 = shstW<64>(r0, i0, j, k);
            r1 = shstW<64>(r1, i1, j, k);
        }
    cmpex32(r0, r1, true);                 // k=128, j=64
#pragma unroll
    for (int j = 32; j > 0; j >>= 1) {
        r0 = shstW<64>(r0, i0, j, 128);
        r1 = shstW<64>(r1, i1, j, 128);
    }
}
__device__ __forceinline__ void sort256d(uint32_t &r0, uint32_t &r1,
                                         uint32_t &r2, uint32_t &r3, int lane) {
    const int i0 = lane, i1 = lane + 64, i2 = lane + 128, i3 = lane + 192;
#pragma unroll
    for (int k = 2; k <= 64; k <<= 1)
#pragma unroll
        for (int j = k >> 1; j > 0; j >>= 1) {
            r0 = shstW<64>(r0, i0, j, k);
            r1 = shstW<64>(r1, i1, j, k);
            r2 = shstW<64>(r2, i2, j, k);
            r3 = shstW<64>(r3, i3, j, k);
        }
    cmpex32(r0, r1, true);                 // k=128, j=64
    cmpex32(r2, r3, false);
#pragma unroll
    for (int j = 32; j > 0; j >>= 1) {
        r0 = shstW<64>(r0, i0, j, 128);
        r1 = shstW<64>(r1, i1, j, 128);
        r2 = shstW<64>(r2, i2, j, 128);
        r3 = shstW<64>(r3, i3, j, 128);
    }
    cmpex32(r0, r2, true); cmpex32(r1, r3, true);   // k=256, j=128
    cmpex32(r0, r1, true); cmpex32(r2, r3, true);   // k=256, j=64
#pragma unroll
    for (int j = 32; j > 0; j >>= 1) {
        r0 = shstW<64>(r0, i0, j, 256);
        r1 = shstW<64>(r1, i1, j, 256);
        r2 = shstW<64>(r2, i2, j, 256);
        r3 = shstW<64>(r3, i3, j, 256);
    }
}

__global__ __launch_bounds__(NTHREADS, 8) void adaptive_topk_kernel(
    const float* __restrict__ in, int* __restrict__ out_idx, int* __restrict__ out_k)
{
    __shared__ uint32_t A32[NBINS / 2];   // 8 KB packed u16 bins (swizzled storage)
    __shared__ uint32_t keys[KEYCAP];     // 6 KB u32 group-scatter keys
    __shared__ uint16_t outbuf[KSEL];     // 2 KB sorted indices staging
    __shared__ uint32_t glist[GLCAP];     // (n<<16)|base per active group
    __shared__ uint32_t jlist[4 * JOBCAP];// 4 slot entries per job
    __shared__ uint32_t jtypes[JOBCAP];   // 0=S(4x16) 1=M(2x32) 2=L64 3=XL128 4=XXL256
    __shared__ uint32_t wavetot[4];
    __shared__ float wsum[4], wsum2[4];
    __shared__ int sh_d1, sh_ng, sh_gp, sh_fb, sh_nj;

    const int row  = blockIdx.x;
    const int tid  = threadIdx.x;
    const int lane = tid & 63;
    const int wv   = tid >> 6;
    const float* __restrict__ rowp = in + (size_t)row * ROWLEN;
    int* __restrict__ orow = out_idx + (size_t)row * KSEL;
    const float4* r4 = (const float4*)rowp;

    const uint4 z0 = {0u, 0u, 0u, 0u};
    ((uint4*)A32)[tid] = z0;              // clear 2048 words (bijective: order-free)
    ((uint4*)A32)[tid + 256] = z0;
    if (tid == 0) { sh_ng = 0; sh_gp = 0; sh_fb = 0; }
    __syncthreads();

    // ---- pass 1 over input: 12-bit histogram (packed u16, swizzled) + moments.
    //      Values NOT kept in registers (scratch hazard) - re-read later.
    float s = 0.0f, s2 = 0.0f;
#pragma unroll
    for (int it = 0; it < 4; ++it) {
        float4 v = r4[tid + 256 * it];
        s += (v.x + v.y) + (v.z + v.w);
        s2 = fmaf(v.x, v.x, fmaf(v.y, v.y, fmaf(v.z, v.z, fmaf(v.w, v.w, s2))));
        uint32_t bx = f2u_sortable(v.x) >> 20, by = f2u_sortable(v.y) >> 20;
        uint32_t bz = f2u_sortable(v.z) >> 20, bw = f2u_sortable(v.w) >> 20;
        atomicAdd(&A32[aswz(bx >> 1)], (bx & 1) ? (1u << 16) : 1u);
        atomicAdd(&A32[aswz(by >> 1)], (by & 1) ? (1u << 16) : 1u);
        atomicAdd(&A32[aswz(bz >> 1)], (bz & 1) ? (1u << 16) : 1u);
        atomicAdd(&A32[aswz(bw >> 1)], (bw & 1) ? (1u << 16) : 1u);
    }
    for (int off = 32; off > 0; off >>= 1) {
        s  += __shfl_down(s, off);
        s2 += __shfl_down(s2, off);
    }
    if (lane == 0) { wsum[wv] = s; wsum2[wv] = s2; }
    __syncthreads();                      // hist + wsum complete
    if (tid == 0) {
        double S  = (double)wsum[0] + wsum[1] + wsum[2] + wsum[3];
        double S2 = (double)wsum2[0] + wsum2[1] + wsum2[2] + wsum2[3];
        double var = (S2 - S * S / (double)ROWLEN) / (double)(ROWLEN - 1);
        float sp = log1pf(expf((float)var));
        float ka = 512.0f * (1.0f + 0.1f * sp);
        ka = fminf(fmaxf(ka, 128.0f), 1024.0f);
        out_k[row] = (int)ka;
    }

    // ---- suffix scan over 4096 bins; boundary digit d1; bases into A32 ----
    uint32_t hww[8];                       // my 16 bins, packed (static-indexed)
    {
        uint4 h0 = ((uint4*)A32)[swb(2 * tid)];
        uint4 h1 = ((uint4*)A32)[swb(2 * tid + 1)];
        hww[0] = h0.x; hww[1] = h0.y; hww[2] = h0.z; hww[3] = h0.w;
        hww[4] = h1.x; hww[5] = h1.y; hww[6] = h1.z; hww[7] = h1.w;
    }
    uint32_t csum = 0;
#pragma unroll
    for (int q = 0; q < 8; ++q) csum += (hww[q] & 0xFFFFu) + (hww[q] >> 16);
    uint32_t incl = csum;                 // inclusive suffix over chunk sums in wave
#pragma unroll
    for (int off = 1; off < 64; off <<= 1) {
        uint32_t t = __shfl_down(incl, off);
        if (lane + off < 64) incl += t;
    }
    if (lane == 0) wavetot[wv] = incl;
    __syncthreads();
    uint32_t later = 0;
    for (int w2 = wv + 1; w2 < 4; ++w2) later += wavetot[w2];
    const uint32_t R = (incl - csum) + later;   // elems in bins after my chunk
    // Guard: bins >= d1 (and the boundary itself) live only in chunks with
    // R < KSEL; other threads' bases are never read. ~75% of threads skip.
    if (R < KSEL) {
        uint32_t run = R;
#pragma unroll
        for (int q = 7; q >= 0; --q) {
            uint32_t h_hi = hww[q] >> 16, h_lo = hww[q] & 0xFFFFu;
            uint32_t base_hi = run;
            if (run < KSEL && KSEL <= run + h_hi) sh_d1 = 16 * tid + 2 * q + 1;
            run += h_hi;
            uint32_t base_lo = run;
            if (run < KSEL && KSEL <= run + h_lo) sh_d1 = 16 * tid + 2 * q;
            run += h_lo;
            A32[aswz(8 * tid + q)] = (base_hi << 16) | base_lo;
        }
    }
    __syncthreads();                      // bases + sh_d1 visible

    const int d1 = sh_d1;

    // ---- group list build (guarded; bases by running subtraction) ----
    if (R < KSEL) {
        uint32_t run2 = R + csum;
#pragma unroll
        for (int b = 0; b < 16; ++b) {
            uint32_t n = (hww[b >> 1] >> ((b & 1) * 16)) & 0xFFFFu;
            run2 -= n;                    // = base of bin g
            int g = 16 * tid + b;
            if (g >= d1 && n > 0) {
                if (n > 256) sh_fb = 1;
                int p = atomicAdd(&sh_ng, 1);
                if (p < GLCAP) glist[p] = (n << 16) | run2;
            }
        }
    }
    // ---- pass 2 over input (cache-hot re-read): grouped scatter, u32 keys ----
#pragma unroll
    for (int it = 0; it < 4; ++it) {
        float4 v = r4[tid + 256 * it];
        const int idx0 = 4 * (tid + 256 * it);
#pragma unroll
        for (int e = 0; e < 4; ++e) {
            float f = (e == 0) ? v.x : (e == 1) ? v.y : (e == 2) ? v.z : v.w;
            uint32_t u = f2u_sortable(f);
            int g = (int)(u >> 20);
            if (g >= d1) {
                uint32_t old = atomicAdd(&A32[aswz(g >> 1)], (g & 1) ? (1u << 16) : 1u);
                uint32_t pos = (g & 1) ? (old >> 16) : (old & 0xFFFFu);
                if (pos < KEYCAP)
                    keys[pos] = (u << 12) | (uint32_t)(ROWLEN - 1 - (idx0 + e));
            }
        }
    }
    __syncthreads();                      // keys + glist complete

    // ---- wave-parallel job packer (ballot/popcount; no serial walk) ----
    if (wv == 0) {
        int ng0 = sh_ng;
        if (ng0 > GLCAP) sh_fb = 1;
        else {
            uint32_t e = (lane < ng0) ? glist[lane] : 0u;
            uint32_t n = e >> 16;
            bool isS = (lane < ng0) && (n <= 16);
            bool isM = (lane < ng0) && (n > 16) && (n <= 32);
            bool isL = (lane < ng0) && (n > 32);
            u64 mS = __ballot(isS), mM = __ballot(isM), mL = __ballot(isL);
            int nS = __popcll(mS), nM = __popcll(mM), nL = __popcll(mL);
            int nSj = (nS + 3) >> 2, nMj = (nM + 1) >> 1;
            int totSM = nSj + nMj;
            const u64 lm = (1ull << lane) - 1ull;
            // clear partial-fill slots first (wave-lockstep: clears precede writes)
            for (int q = lane; q < 4 * totSM; q += 64) jlist[q] = 0;
            if (isS) {
                int r = __popcll(mS & lm);
                jlist[4 * (r >> 2) + (r & 3)] = e;
                if ((r & 3) == 0) jtypes[r >> 2] = 0;
            }
            if (isM) {
                int r = __popcll(mM & lm);
                jlist[4 * (nSj + (r >> 1)) + (r & 1)] = e;
                if ((r & 1) == 0) jtypes[nSj + (r >> 1)] = 1;
            }
            if (isL) {
                int r = __popcll(mL & lm);
                jlist[4 * (totSM + r)] = e;
                jtypes[totSM + r] = (n <= 64) ? 2u : (n <= 128) ? 3u : 4u;
            }
            if (lane == 0) sh_nj = totSM + nL;
        }
    }
    __syncthreads();                      // jobs + final sh_fb visible

    if (!sh_fb) {
        // ---- per-job in-wave sorts -> LDS outbuf (no barriers) ----
        const int nj = sh_nj;
        for (;;) {
            int j = 0;
            if (lane == 0) j = atomicAdd(&sh_gp, 1);
            j = __shfl(j, 0);
            if (j >= nj) break;
            uint32_t ty = jtypes[j];
            if (ty == 0) {                 // 4 groups x width-16
                int slot = lane >> 4, subl = lane & 15;
                uint32_t e = jlist[4 * j + slot];
                int n = (int)(e >> 16), base = (int)(e & 0xFFFFu);
                uint32_t r0 = (subl < n) ? keys[base + subl] : 0u;
                sort16d(r0, subl);
                int quota = min(n, KSEL - base);
                if (subl < quota)
                    outbuf[base + subl] = (uint16_t)((ROWLEN - 1) - (int)(r0 & 0xFFFu));
            } else if (ty == 1) {          // 2 groups x width-32
                int slot = lane >> 5, subl = lane & 31;
                uint32_t e = jlist[4 * j + slot];
                int n = (int)(e >> 16), base = (int)(e & 0xFFFFu);
                uint32_t r0 = (subl < n) ? keys[base + subl] : 0u;
                sort32d(r0, subl);
                int quota = min(n, KSEL - base);
                if (subl < quota)
                    outbuf[base + subl] = (uint16_t)((ROWLEN - 1) - (int)(r0 & 0xFFFu));
            } else {
                uint32_t e = jlist[4 * j];
                int n = (int)(e >> 16), base = (int)(e & 0xFFFFu);
                int quota = min(n, KSEL - base);
                const int i0 = lane, i1 = lane + 64, i2 = lane + 128, i3 = lane + 192;
                if (ty == 2) {
                    uint32_t r0 = (i0 < n) ? keys[base + i0] : 0u;
                    sort64d(r0, lane);
                    if (i0 < quota)
                        outbuf[base + i0] = (uint16_t)((ROWLEN - 1) - (int)(r0 & 0xFFFu));
                } else if (ty == 3) {
                    uint32_t r0 = (i0 < n) ? keys[base + i0] : 0u;
                    uint32_t r1 = (i1 < n) ? keys[base + i1] : 0u;
                    sort128d(r0, r1, lane);
                    if (i0 < quota)
                        outbuf[base + i0] = (uint16_t)((ROWLEN - 1) - (int)(r0 & 0xFFFu));
                    if (i1 < quota)
                        outbuf[base + i1] = (uint16_t)((ROWLEN - 1) - (int)(r1 & 0xFFFu));
                } else {
                    uint32_t r0 = (i0 < n) ? keys[base + i0] : 0u;
                    uint32_t r1 = (i1 < n) ? keys[base + i1] : 0u;
                    uint32_t r2 = (i2 < n) ? keys[base + i2] : 0u;
                    uint32_t r3 = (i3 < n) ? keys[base + i3] : 0u;
                    sort256d(r0, r1, r2, r3, lane);
                    if (i0 < quota)
                        outbuf[base + i0] = (uint16_t)((ROWLEN - 1) - (int)(r0 & 0xFFFu));
                    if (i1 < quota)
                        outbuf[base + i1] = (uint16_t)((ROWLEN - 1) - (int)(r1 & 0xFFFu));
                    if (i2 < quota)
                        outbuf[base + i2] = (uint16_t)((ROWLEN - 1) - (int)(r2 & 0xFFFu));
                    if (i3 < quota)
                        outbuf[base + i3] = (uint16_t)((ROWLEN - 1) - (int)(r3 & 0xFFFu));
                }
            }
        }
        __syncthreads();                  // outbuf complete
        // ---- single coalesced row store: ushort4 (LDS) -> int4 (global) ----
        ushort4 t4 = ((const ushort4*)outbuf)[tid];
        int4 ov = { (int)t4.x, (int)t4.y, (int)t4.z, (int)t4.w };
        ((int4*)orow)[tid] = ov;
    } else {
        // ---- exact cooperative fallback (statistically never taken) ----
        if (tid < 64) {
            u64 prev = ~0ull;
            for (int r = 0; r < KSEL; ++r) {
                u64 best = 0;
                for (int c = lane; c < ROWLEN; c += 64) {
                    u64 K = ((u64)f2u_sortable(rowp[c]) << 12) | (u64)(ROWLEN - 1 - c);
                    if (K < prev && K > best) best = K;
                }
                for (int off = 32; off > 0; off >>= 1) {
                    u64 o = __shfl_xor(best, off, 64);
                    best = best > o ? best : o;
                }
                if (lane == 0) orow[r] = (ROWLEN - 1) - (int)(best & 0xFFFu);
                prev = best;
            }
        }
    }
}

extern "C" void kernel_launch(void* const* d_in, const int* in_sizes, int n_in,
                              void* d_out, int out_size, void* d_ws, size_t ws_size,
                              hipStream_t stream) {
    const float* in = (const float*)d_in[0];
    const int B = in_sizes[0] / (ROWLEN * ROWLEN);   // 4
    const int nrows = B * ROWLEN;                    // 16384
    int* out = (int*)d_out;
    int* out_idx = out;                              // B*L*KSEL
    int* out_k   = out + (size_t)nrows * KSEL;       // B*L
    adaptive_topk_kernel<<<dim3(nrows), dim3(NTHREADS), 0, stream>>>(in, out_idx, out_k);
}

// Round 12
// 191.093 us; speedup vs baseline: 1.2365x; 1.1411x over previous
//
#include <hip/hip_runtime.h>
#include <stdint.h>

#define ROWLEN 4096
#define KSEL   1024
#define NTHREADS 256
#define NBINS  4096      // 12-bit digit = v >> 20
#define KEYCAP 1536
#define GLCAP  64        // >64 active groups -> fallback (never for N(0,1))
#define JOBCAP 64
typedef unsigned long long u64;

// Monotonic float->uint map: order(f) preserved as unsigned compare.
__device__ __forceinline__ uint32_t f2u_sortable(float f) {
    uint32_t u = __float_as_uint(f);
    return u ^ ((int32_t)u < 0 ? 0xFFFFFFFFu : 0x80000000u);
}

// A32 bank swizzle: involution on word index, preserves 4-word blocks.
__device__ __forceinline__ int aswz(int w) { return w ^ ((w >> 3) & 0x1C); }
__device__ __forceinline__ int swb(int B) { return B ^ ((B >> 3) & 7); }   // block form

__device__ __forceinline__ void cmpex32(uint32_t &a, uint32_t &b, bool maxFirst) {
    uint32_t lo = a < b ? a : b, hi = a < b ? b : a;
    a = maxFirst ? hi : lo;
    b = maxFirst ? lo : hi;
}

// Shuffle stage for 4-elem/lane row-major layout: element i=4*subl+e, lane
// partner subl^(j>>2) within W-lane segment. Keys distinct within a group.
template<int W>
__device__ __forceinline__ uint32_t shst4(uint32_t r, int i, int j, int k) {
    uint32_t o = __shfl_xor(r, j >> 2, W);
    bool takeMax = (((i & j) == 0) == ((i & k) == 0));
    return ((r > o) == takeMax) ? r : o;
}

// Descending bitonic sort of P=2^LOGP keys held as 4 regs/lane (i = 4*subl+e)
// across W=P/4 lanes. j=1,2 in-register; j>=4 via shfl at width W.
// Named scalars only (no arrays -> no scratch risk).
template<int LOGP>
__device__ __forceinline__ void sortP4(uint32_t &r0, uint32_t &r1,
                                       uint32_t &r2, uint32_t &r3, int subl) {
    constexpr int P = 1 << LOGP;
    constexpr int W = P >> 2;
    const int i0 = 4 * subl, i1 = i0 + 1, i2 = i0 + 2, i3 = i0 + 3;
#pragma unroll
    for (int k = 2; k <= P; k <<= 1) {
#pragma unroll
        for (int j = k >> 1; j > 0; j >>= 1) {
            if (j == 1) {
                cmpex32(r0, r1, (i0 & k) == 0);
                cmpex32(r2, r3, (i2 & k) == 0);
            } else if (j == 2) {
                cmpex32(r0, r2, (i0 & k) == 0);
                cmpex32(r1, r3, (i1 & k) == 0);
            } else {
                r0 = shst4<W>(r0, i0, j, k);
                r1 = shst4<W>(r1, i1, j, k);
                r2 = shst4<W>(r2, i2, j, k);
                r3 = shst4<W>(r3, i3, j, k);
            }
        }
    }
}

__global__ __launch_bounds__(NTHREADS, 8) void adaptive_topk_kernel(
    const float* __restrict__ in, int* __restrict__ out_idx, int* __restrict__ out_k)
{
    __shared__ uint32_t A32[NBINS / 2];   // 8 KB packed u16 bins (swizzled storage)
    __shared__ uint32_t keys[KEYCAP];     // 6 KB u32 group-scatter keys
    __shared__ uint16_t outbuf[KSEL];     // 2 KB sorted indices staging
    __shared__ uint32_t glist[GLCAP];     // (n<<16)|base per active group
    __shared__ uint32_t glist2[GLCAP];    // class-sorted groups
    __shared__ uint32_t jinfo[JOBCAP];    // type(3b) | start<<3 (6b) | nslots<<9 (5b)
    __shared__ uint32_t wavetot[4];
    __shared__ float wsum[4], wsum2[4];
    __shared__ int sh_d1, sh_ng, sh_gp, sh_fb, sh_nj;

    const int row  = blockIdx.x;
    const int tid  = threadIdx.x;
    const int lane = tid & 63;
    const int wv   = tid >> 6;
    const float* __restrict__ rowp = in + (size_t)row * ROWLEN;
    int* __restrict__ orow = out_idx + (size_t)row * KSEL;
    const float4* r4 = (const float4*)rowp;

    const uint4 z0 = {0u, 0u, 0u, 0u};
    ((uint4*)A32)[tid] = z0;              // clear 2048 words (bijective: order-free)
    ((uint4*)A32)[tid + 256] = z0;
    if (tid == 0) { sh_ng = 0; sh_gp = 0; sh_fb = 0; }
    __syncthreads();

    // ---- pass 1 over input: 12-bit histogram (packed u16, swizzled) + moments.
    //      Values NOT kept in registers (scratch hazard) - re-read later.
    float s = 0.0f, s2 = 0.0f;
#pragma unroll
    for (int it = 0; it < 4; ++it) {
        float4 v = r4[tid + 256 * it];
        s += (v.x + v.y) + (v.z + v.w);
        s2 = fmaf(v.x, v.x, fmaf(v.y, v.y, fmaf(v.z, v.z, fmaf(v.w, v.w, s2))));
        uint32_t bx = f2u_sortable(v.x) >> 20, by = f2u_sortable(v.y) >> 20;
        uint32_t bz = f2u_sortable(v.z) >> 20, bw = f2u_sortable(v.w) >> 20;
        atomicAdd(&A32[aswz(bx >> 1)], (bx & 1) ? (1u << 16) : 1u);
        atomicAdd(&A32[aswz(by >> 1)], (by & 1) ? (1u << 16) : 1u);
        atomicAdd(&A32[aswz(bz >> 1)], (bz & 1) ? (1u << 16) : 1u);
        atomicAdd(&A32[aswz(bw >> 1)], (bw & 1) ? (1u << 16) : 1u);
    }
    for (int off = 32; off > 0; off >>= 1) {
        s  += __shfl_down(s, off);
        s2 += __shfl_down(s2, off);
    }
    if (lane == 0) { wsum[wv] = s; wsum2[wv] = s2; }
    __syncthreads();                      // hist + wsum complete
    if (tid == 0) {
        double S  = (double)wsum[0] + wsum[1] + wsum[2] + wsum[3];
        double S2 = (double)wsum2[0] + wsum2[1] + wsum2[2] + wsum2[3];
        double var = (S2 - S * S / (double)ROWLEN) / (double)(ROWLEN - 1);
        float sp = log1pf(expf((float)var));
        float ka = 512.0f * (1.0f + 0.1f * sp);
        ka = fminf(fmaxf(ka, 128.0f), 1024.0f);
        out_k[row] = (int)ka;
    }

    // ---- suffix scan over 4096 bins; boundary digit d1; bases into A32 ----
    uint32_t hww[8];                       // my 16 bins, packed (static-indexed)
    {
        uint4 h0 = ((uint4*)A32)[swb(2 * tid)];
        uint4 h1 = ((uint4*)A32)[swb(2 * tid + 1)];
        hww[0] = h0.x; hww[1] = h0.y; hww[2] = h0.z; hww[3] = h0.w;
        hww[4] = h1.x; hww[5] = h1.y; hww[6] = h1.z; hww[7] = h1.w;
    }
    uint32_t csum = 0;
#pragma unroll
    for (int q = 0; q < 8; ++q) csum += (hww[q] & 0xFFFFu) + (hww[q] >> 16);
    uint32_t incl = csum;                 // inclusive suffix over chunk sums in wave
#pragma unroll
    for (int off = 1; off < 64; off <<= 1) {
        uint32_t t = __shfl_down(incl, off);
        if (lane + off < 64) incl += t;
    }
    if (lane == 0) wavetot[wv] = incl;
    __syncthreads();
    uint32_t later = 0;
    for (int w2 = wv + 1; w2 < 4; ++w2) later += wavetot[w2];
    const uint32_t R = (incl - csum) + later;   // elems in bins after my chunk
    // Guard: bins >= d1 live only in chunks with R < KSEL (~75% threads skip).
    if (R < KSEL) {
        uint32_t run = R;
#pragma unroll
        for (int q = 7; q >= 0; --q) {
            uint32_t h_hi = hww[q] >> 16, h_lo = hww[q] & 0xFFFFu;
            uint32_t base_hi = run;
            if (run < KSEL && KSEL <= run + h_hi) sh_d1 = 16 * tid + 2 * q + 1;
            run += h_hi;
            uint32_t base_lo = run;
            if (run < KSEL && KSEL <= run + h_lo) sh_d1 = 16 * tid + 2 * q;
            run += h_lo;
            A32[aswz(8 * tid + q)] = (base_hi << 16) | base_lo;
        }
    }
    __syncthreads();                      // bases + sh_d1 visible

    const int d1 = sh_d1;

    // ---- group list build (guarded; bases by running subtraction) ----
    if (R < KSEL) {
        uint32_t run2 = R + csum;
#pragma unroll
        for (int b = 0; b < 16; ++b) {
            uint32_t n = (hww[b >> 1] >> ((b & 1) * 16)) & 0xFFFFu;
            run2 -= n;                    // = base of bin g
            int g = 16 * tid + b;
            if (g >= d1 && n > 0) {
                if (n > 256) sh_fb = 1;
                int p = atomicAdd(&sh_ng, 1);
                if (p < GLCAP) glist[p] = (n << 16) | run2;
            }
        }
    }
    // ---- pass 2 over input (cache-hot re-read): grouped scatter, u32 keys ----
#pragma unroll
    for (int it = 0; it < 4; ++it) {
        float4 v = r4[tid + 256 * it];
        const int idx0 = 4 * (tid + 256 * it);
#pragma unroll
        for (int e = 0; e < 4; ++e) {
            float f = (e == 0) ? v.x : (e == 1) ? v.y : (e == 2) ? v.z : v.w;
            uint32_t u = f2u_sortable(f);
            int g = (int)(u >> 20);
            if (g >= d1) {
                uint32_t old = atomicAdd(&A32[aswz(g >> 1)], (g & 1) ? (1u << 16) : 1u);
                uint32_t pos = (g & 1) ? (old >> 16) : (old & 0xFFFFu);
                if (pos < KEYCAP)
                    keys[pos] = (u << 12) | (uint32_t)(ROWLEN - 1 - (idx0 + e));
            }
        }
    }
    __syncthreads();                      // keys + glist complete

    // ---- wave-parallel 5-class packer: A n<=16 (16/job), B <=32 (8/job),
    //      C <=64 (4/job), D <=128 (2/job), E <=256 (1/job) ----
    if (wv == 0) {
        int ng0 = sh_ng;
        if (ng0 > GLCAP) sh_fb = 1;
        else {
            uint32_t e = (lane < ng0) ? glist[lane] : 0u;
            uint32_t n = e >> 16;
            bool vA = (n >= 1)  && (n <= 16);
            bool vB = (n > 16)  && (n <= 32);
            bool vC = (n > 32)  && (n <= 64);
            bool vD = (n > 64)  && (n <= 128);
            bool vE = (n > 128) && (n <= 256);
            u64 mA = __ballot(vA), mB = __ballot(vB), mC = __ballot(vC);
            u64 mD = __ballot(vD), mE = __ballot(vE);
            int cA = __popcll(mA), cB = __popcll(mB), cC = __popcll(mC);
            int cD = __popcll(mD), cE = __popcll(mE);
            const u64 lm = (1ull << lane) - 1ull;
            int pos = -1;
            if (vA) pos = __popcll(mA & lm);
            else if (vB) pos = cA + __popcll(mB & lm);
            else if (vC) pos = cA + cB + __popcll(mC & lm);
            else if (vD) pos = cA + cB + cC + __popcll(mD & lm);
            else if (vE) pos = cA + cB + cC + cD + __popcll(mE & lm);
            if (pos >= 0) glist2[pos] = e;
            if (lane == 0) {
                int nj = 0, cb = 0;
                for (int q = 0; q < cA; q += 16)
                    jinfo[nj++] = 0u | ((uint32_t)(cb + q) << 3) | ((uint32_t)min(16, cA - q) << 9);
                cb += cA;
                for (int q = 0; q < cB; q += 8)
                    jinfo[nj++] = 1u | ((uint32_t)(cb + q) << 3) | ((uint32_t)min(8, cB - q) << 9);
                cb += cB;
                for (int q = 0; q < cC; q += 4)
                    jinfo[nj++] = 2u | ((uint32_t)(cb + q) << 3) | ((uint32_t)min(4, cC - q) << 9);
                cb += cC;
                for (int q = 0; q < cD; q += 2)
                    jinfo[nj++] = 3u | ((uint32_t)(cb + q) << 3) | ((uint32_t)min(2, cD - q) << 9);
                cb += cD;
                for (int q = 0; q < cE; ++q)
                    jinfo[nj++] = 4u | ((uint32_t)(cb + q) << 3) | (1u << 9);
                sh_nj = nj;
            }
        }
    }
    __syncthreads();                      // jobs + final sh_fb visible

    if (!sh_fb) {
        // ---- per-job packed in-wave sorts -> LDS outbuf (no barriers) ----
#define RUN_SORT(LOGP, SH)                                                    \
        {                                                                     \
            int slot = lane >> (SH), subl = lane & ((1 << (SH)) - 1);         \
            uint32_t e2 = (slot < ns) ? glist2[st + slot] : 0u;               \
            int n = (int)(e2 >> 16), base = (int)(e2 & 0xFFFFu);              \
            const int i0 = 4 * subl, i1 = i0 + 1, i2 = i0 + 2, i3 = i0 + 3;   \
            uint32_t r0 = (i0 < n) ? keys[base + i0] : 0u;                    \
            uint32_t r1 = (i1 < n) ? keys[base + i1] : 0u;                    \
            uint32_t r2 = (i2 < n) ? keys[base + i2] : 0u;                    \
            uint32_t r3 = (i3 < n) ? keys[base + i3] : 0u;                    \
            sortP4<LOGP>(r0, r1, r2, r3, subl);                               \
            int quota = min(n, KSEL - base);                                  \
            if (i0 < quota) outbuf[base + i0] =                               \
                (uint16_t)((ROWLEN - 1) - (int)(r0 & 0xFFFu));                \
            if (i1 < quota) outbuf[base + i1] =                               \
                (uint16_t)((ROWLEN - 1) - (int)(r1 & 0xFFFu));                \
            if (i2 < quota) outbuf[base + i2] =                               \
                (uint16_t)((ROWLEN - 1) - (int)(r2 & 0xFFFu));                \
            if (i3 < quota) outbuf[base + i3] =                               \
                (uint16_t)((ROWLEN - 1) - (int)(r3 & 0xFFFu));                \
        }
        const int nj = sh_nj;
        for (;;) {
            int j = 0;
            if (lane == 0) j = atomicAdd(&sh_gp, 1);
            j = __shfl(j, 0);
            if (j >= nj) break;
            uint32_t info = jinfo[j];
            int ty = (int)(info & 7u);
            int st = (int)((info >> 3) & 63u);
            int ns = (int)((info >> 9) & 31u);
            if (ty == 0)      RUN_SORT(4, 2)   // P=16,  16 groups/job
            else if (ty == 1) RUN_SORT(5, 3)   // P=32,  8 groups/job
            else if (ty == 2) RUN_SORT(6, 4)   // P=64,  4 groups/job
            else if (ty == 3) RUN_SORT(7, 5)   // P=128, 2 groups/job
            else              RUN_SORT(8, 6)   // P=256, 1 group/job
        }
#undef RUN_SORT
        __syncthreads();                  // outbuf complete
        // ---- single coalesced row store: ushort4 (LDS) -> int4 (global) ----
        ushort4 t4 = ((const ushort4*)outbuf)[tid];
        int4 ov = { (int)t4.x, (int)t4.y, (int)t4.z, (int)t4.w };
        ((int4*)orow)[tid] = ov;
    } else {
        // ---- exact cooperative fallback (statistically never taken) ----
        if (tid < 64) {
            u64 prev = ~0ull;
            for (int r = 0; r < KSEL; ++r) {
                u64 best = 0;
                for (int c = lane; c < ROWLEN; c += 64) {
                    u64 K = ((u64)f2u_sortable(rowp[c]) << 12) | (u64)(ROWLEN - 1 - c);
                    if (K < prev && K > best) best = K;
                }
                for (int off = 32; off > 0; off >>= 1) {
                    u64 o = __shfl_xor(best, off, 64);
                    best = best > o ? best : o;
                }
                if (lane == 0) orow[r] = (ROWLEN - 1) - (int)(best & 0xFFFu);
                prev = best;
            }
        }
    }
}

extern "C" void kernel_launch(void* const* d_in, const int* in_sizes, int n_in,
                              void* d_out, int out_size, void* d_ws, size_t ws_size,
                              hipStream_t stream) {
    const float* in = (const float*)d_in[0];
    const int B = in_sizes[0] / (ROWLEN * ROWLEN);   // 4
    const int nrows = B * ROWLEN;                    // 16384
    int* out = (int*)d_out;
    int* out_idx = out;                              // B*L*KSEL
    int* out_k   = out + (size_t)nrows * KSEL;       // B*L
    adaptive_topk_kernel<<<dim3(nrows), dim3(NTHREADS), 0, stream>>>(in, out_idx, out_k);
}

// Round 13
// 183.572 us; speedup vs baseline: 1.2872x; 1.0410x over previous
//
#include <hip/hip_runtime.h>
#include <stdint.h>

#define ROWLEN 4096
#define KSEL   1024
#define NTHREADS 256
#define NBINS  4096      // 12-bit digit = v >> 20
#define KEYCAP 1536
#define GLCAP  64        // >64 active groups -> fallback (never for N(0,1))
#define JOBCAP 64
typedef unsigned long long u64;

// Monotonic float->uint map: order(f) preserved as unsigned compare.
__device__ __forceinline__ uint32_t f2u_sortable(float f) {
    uint32_t u = __float_as_uint(f);
    return u ^ ((int32_t)u < 0 ? 0xFFFFFFFFu : 0x80000000u);
}

// A32 bank swizzle: involution on word index, preserves 4-word blocks.
__device__ __forceinline__ int aswz(int w) { return w ^ ((w >> 3) & 0x1C); }
__device__ __forceinline__ int swb(int B) { return B ^ ((B >> 3) & 7); }   // block form

__device__ __forceinline__ void cmpex32(uint32_t &a, uint32_t &b, bool maxFirst) {
    uint32_t lo = a < b ? a : b, hi = a < b ? b : a;
    a = maxFirst ? hi : lo;
    b = maxFirst ? lo : hi;
}

// Shuffle stage for 4-elem/lane row-major layout: element i=4*subl+e, lane
// partner subl^(j>>2) within W-lane segment. Keys distinct within a group.
template<int W>
__device__ __forceinline__ uint32_t shst4(uint32_t r, int i, int j, int k) {
    uint32_t o = __shfl_xor(r, j >> 2, W);
    bool takeMax = (((i & j) == 0) == ((i & k) == 0));
    return ((r > o) == takeMax) ? r : o;
}

// Descending bitonic sort of P=2^LOGP keys held as 4 regs/lane (i = 4*subl+e)
// across W=P/4 lanes. j=1,2 in-register; j>=4 via shfl at width W.
template<int LOGP>
__device__ __forceinline__ void sortP4(uint32_t &r0, uint32_t &r1,
                                       uint32_t &r2, uint32_t &r3, int subl) {
    constexpr int P = 1 << LOGP;
    constexpr int W = P >> 2;
    const int i0 = 4 * subl, i1 = i0 + 1, i2 = i0 + 2, i3 = i0 + 3;
#pragma unroll
    for (int k = 2; k <= P; k <<= 1) {
#pragma unroll
        for (int j = k >> 1; j > 0; j >>= 1) {
            if (j == 1) {
                cmpex32(r0, r1, (i0 & k) == 0);
                cmpex32(r2, r3, (i2 & k) == 0);
            } else if (j == 2) {
                cmpex32(r0, r2, (i0 & k) == 0);
                cmpex32(r1, r3, (i1 & k) == 0);
            } else {
                r0 = shst4<W>(r0, i0, j, k);
                r1 = shst4<W>(r1, i1, j, k);
                r2 = shst4<W>(r2, i2, j, k);
                r3 = shst4<W>(r3, i3, j, k);
            }
        }
    }
}

__global__ __launch_bounds__(NTHREADS, 8) void adaptive_topk_kernel(
    const float* __restrict__ in, int* __restrict__ out_idx, int* __restrict__ out_k)
{
    __shared__ uint32_t A32[NBINS / 2];   // 8 KB packed u16 bins (swizzled storage)
    __shared__ uint32_t keys[KEYCAP];     // 6 KB u32 group-scatter keys
    __shared__ uint16_t outbuf[KSEL];     // 2 KB sorted indices staging
    __shared__ uint32_t glist[GLCAP];     // (n<<16)|base per active group
    __shared__ uint32_t glist2[GLCAP];    // class-sorted groups
    __shared__ uint32_t jinfo[JOBCAP];    // type(3b) | start<<3 (6b) | nslots<<9 (5b)
    __shared__ uint32_t wavetot[4];
    __shared__ float wsum[4], wsum2[4];
    __shared__ int sh_d1, sh_ng, sh_fb, sh_nj;

    const int row  = blockIdx.x;
    const int tid  = threadIdx.x;
    const int lane = tid & 63;
    const int wv   = tid >> 6;
    const float* __restrict__ rowp = in + (size_t)row * ROWLEN;
    int* __restrict__ orow = out_idx + (size_t)row * KSEL;
    const float4* r4 = (const float4*)rowp;

    const uint4 z0 = {0u, 0u, 0u, 0u};
    ((uint4*)A32)[tid] = z0;              // clear 2048 words (bijective: order-free)
    ((uint4*)A32)[tid + 256] = z0;
    if (tid == 0) { sh_ng = 0; sh_fb = 0; }
    __syncthreads();

    // ---- pass 1 over input: 12-bit histogram (packed u16, swizzled) + moments.
    //      Values NOT kept in registers (scratch hazard) - re-read later.
    float s = 0.0f, s2 = 0.0f;
#pragma unroll
    for (int it = 0; it < 4; ++it) {
        float4 v = r4[tid + 256 * it];
        s += (v.x + v.y) + (v.z + v.w);
        s2 = fmaf(v.x, v.x, fmaf(v.y, v.y, fmaf(v.z, v.z, fmaf(v.w, v.w, s2))));
        uint32_t bx = f2u_sortable(v.x) >> 20, by = f2u_sortable(v.y) >> 20;
        uint32_t bz = f2u_sortable(v.z) >> 20, bw = f2u_sortable(v.w) >> 20;
        atomicAdd(&A32[aswz(bx >> 1)], (bx & 1) ? (1u << 16) : 1u);
        atomicAdd(&A32[aswz(by >> 1)], (by & 1) ? (1u << 16) : 1u);
        atomicAdd(&A32[aswz(bz >> 1)], (bz & 1) ? (1u << 16) : 1u);
        atomicAdd(&A32[aswz(bw >> 1)], (bw & 1) ? (1u << 16) : 1u);
    }
    for (int off = 32; off > 0; off >>= 1) {
        s  += __shfl_down(s, off);
        s2 += __shfl_down(s2, off);
    }
    if (lane == 0) { wsum[wv] = s; wsum2[wv] = s2; }
    __syncthreads();                      // hist + wsum complete
    if (tid == 0) {
        double S  = (double)wsum[0] + wsum[1] + wsum[2] + wsum[3];
        double S2 = (double)wsum2[0] + wsum2[1] + wsum2[2] + wsum2[3];
        double var = (S2 - S * S / (double)ROWLEN) / (double)(ROWLEN - 1);
        float sp = log1pf(expf((float)var));
        float ka = 512.0f * (1.0f + 0.1f * sp);
        ka = fminf(fmaxf(ka, 128.0f), 1024.0f);
        out_k[row] = (int)ka;
    }

    // ---- suffix scan over 4096 bins; boundary digit d1; bases into A32 ----
    uint32_t hww[8];                       // my 16 bins, packed (static-indexed)
    {
        uint4 h0 = ((uint4*)A32)[swb(2 * tid)];
        uint4 h1 = ((uint4*)A32)[swb(2 * tid + 1)];
        hww[0] = h0.x; hww[1] = h0.y; hww[2] = h0.z; hww[3] = h0.w;
        hww[4] = h1.x; hww[5] = h1.y; hww[6] = h1.z; hww[7] = h1.w;
    }
    uint32_t csum = 0;
#pragma unroll
    for (int q = 0; q < 8; ++q) csum += (hww[q] & 0xFFFFu) + (hww[q] >> 16);
    uint32_t incl = csum;                 // inclusive suffix over chunk sums in wave
#pragma unroll
    for (int off = 1; off < 64; off <<= 1) {
        uint32_t t = __shfl_down(incl, off);
        if (lane + off < 64) incl += t;
    }
    if (lane == 0) wavetot[wv] = incl;
    __syncthreads();
    uint32_t later = 0;
    for (int w2 = wv + 1; w2 < 4; ++w2) later += wavetot[w2];
    const uint32_t R = (incl - csum) + later;   // elems in bins after my chunk
    // Guard: bins >= d1 live only in chunks with R < KSEL (~75% threads skip).
    if (R < KSEL) {
        uint32_t run = R;
#pragma unroll
        for (int q = 7; q >= 0; --q) {
            uint32_t h_hi = hww[q] >> 16, h_lo = hww[q] & 0xFFFFu;
            uint32_t base_hi = run;
            if (run < KSEL && KSEL <= run + h_hi) sh_d1 = 16 * tid + 2 * q + 1;
            run += h_hi;
            uint32_t base_lo = run;
            if (run < KSEL && KSEL <= run + h_lo) sh_d1 = 16 * tid + 2 * q;
            run += h_lo;
            A32[aswz(8 * tid + q)] = (base_hi << 16) | base_lo;
        }
    }
    __syncthreads();                      // bases + sh_d1 visible

    const int d1 = sh_d1;

    // ---- group list build (guarded; bases by running subtraction) ----
    if (R < KSEL) {
        uint32_t run2 = R + csum;
#pragma unroll
        for (int b = 0; b < 16; ++b) {
            uint32_t n = (hww[b >> 1] >> ((b & 1) * 16)) & 0xFFFFu;
            run2 -= n;                    // = base of bin g
            int g = 16 * tid + b;
            if (g >= d1 && n > 0) {
                if (n > 256) sh_fb = 1;
                int p = atomicAdd(&sh_ng, 1);
                if (p < GLCAP) glist[p] = (n << 16) | run2;
            }
        }
    }
    // ---- pass 2 over input (cache-hot re-read): grouped scatter, u32 keys ----
#pragma unroll
    for (int it = 0; it < 4; ++it) {
        float4 v = r4[tid + 256 * it];
        const int idx0 = 4 * (tid + 256 * it);
#pragma unroll
        for (int e = 0; e < 4; ++e) {
            float f = (e == 0) ? v.x : (e == 1) ? v.y : (e == 2) ? v.z : v.w;
            uint32_t u = f2u_sortable(f);
            int g = (int)(u >> 20);
            if (g >= d1) {
                uint32_t old = atomicAdd(&A32[aswz(g >> 1)], (g & 1) ? (1u << 16) : 1u);
                uint32_t pos = (g & 1) ? (old >> 16) : (old & 0xFFFFu);
                if (pos < KEYCAP)
                    keys[pos] = (u << 12) | (uint32_t)(ROWLEN - 1 - (idx0 + e));
            }
        }
    }
    __syncthreads();                      // keys + glist complete

    // ---- wave-parallel packer, one class at a time (single live mask) ----
    if (wv == 0) {
        int ng0 = sh_ng;
        if (ng0 > GLCAP) sh_fb = 1;
        else {
            uint32_t e = (lane < ng0) ? glist[lane] : 0u;
            uint32_t n = e >> 16;
            int cls = (lane >= ng0) ? -1 :
                      (n <= 16) ? 0 : (n <= 32) ? 1 : (n <= 64) ? 2 :
                      (n <= 128) ? 3 : 4;
            const u64 lm = (1ull << lane) - 1ull;
            int pos = -1, start = 0, njl = 0;
#pragma unroll
            for (int c = 0; c < 5; ++c) {
                u64 m = __ballot(cls == c);
                int cnt = __popcll(m);
                if (cls == c) pos = start + __popcll(m & lm);
                if (lane == 0) {
                    int per = 16 >> c;     // groups per job: 16,8,4,2,1
                    for (int q = 0; q < cnt; q += per)
                        jinfo[njl++] = (uint32_t)c | ((uint32_t)(start + q) << 3) |
                                       ((uint32_t)min(per, cnt - q) << 9);
                }
                start += cnt;
            }
            if (pos >= 0) glist2[pos] = e;
            if (lane == 0) sh_nj = njl;
        }
    }
    __syncthreads();                      // jobs + final sh_fb visible

    if (!sh_fb) {
        // ---- five per-type loops, ONE sort instantiation each (no co-live
        //      variants -> no spill); static wave-strided job assignment ----
        const int nj = sh_nj;
#define RUN_SORT_T(TY, LOGP, SH)                                              \
        for (int j = wv; j < nj; j += 4) {                                    \
            uint32_t info = jinfo[j];                                         \
            if ((info & 7u) != (uint32_t)(TY)) continue;                      \
            int st = (int)((info >> 3) & 63u);                                \
            int ns = (int)((info >> 9) & 31u);                                \
            int slot = lane >> (SH), subl = lane & ((1 << (SH)) - 1);         \
            uint32_t e2 = (slot < ns) ? glist2[st + slot] : 0u;               \
            int n = (int)(e2 >> 16), base = (int)(e2 & 0xFFFFu);              \
            const int i0 = 4 * subl, i1 = i0 + 1, i2 = i0 + 2, i3 = i0 + 3;   \
            uint32_t r0 = (i0 < n) ? keys[base + i0] : 0u;                    \
            uint32_t r1 = (i1 < n) ? keys[base + i1] : 0u;                    \
            uint32_t r2 = (i2 < n) ? keys[base + i2] : 0u;                    \
            uint32_t r3 = (i3 < n) ? keys[base + i3] : 0u;                    \
            sortP4<LOGP>(r0, r1, r2, r3, subl);                               \
            int quota = min(n, KSEL - base);                                  \
            if (i0 < quota) outbuf[base + i0] =                               \
                (uint16_t)((ROWLEN - 1) - (int)(r0 & 0xFFFu));                \
            if (i1 < quota) outbuf[base + i1] =                               \
                (uint16_t)((ROWLEN - 1) - (int)(r1 & 0xFFFu));                \
            if (i2 < quota) outbuf[base + i2] =                               \
                (uint16_t)((ROWLEN - 1) - (int)(r2 & 0xFFFu));                \
            if (i3 < quota) outbuf[base + i3] =                               \
                (uint16_t)((ROWLEN - 1) - (int)(r3 & 0xFFFu));                \
        }
        RUN_SORT_T(0, 4, 2)   // P=16,  16 groups/job
        RUN_SORT_T(1, 5, 3)   // P=32,  8 groups/job
        RUN_SORT_T(2, 6, 4)   // P=64,  4 groups/job
        RUN_SORT_T(3, 7, 5)   // P=128, 2 groups/job
        RUN_SORT_T(4, 8, 6)   // P=256, 1 group/job
#undef RUN_SORT_T
        __syncthreads();                  // outbuf complete
        // ---- single coalesced row store: ushort4 (LDS) -> int4 (global) ----
        ushort4 t4 = ((const ushort4*)outbuf)[tid];
        int4 ov = { (int)t4.x, (int)t4.y, (int)t4.z, (int)t4.w };
        ((int4*)orow)[tid] = ov;
    } else {
        // ---- exact cooperative fallback (statistically never taken) ----
        if (tid < 64) {
            u64 prev = ~0ull;
            for (int r = 0; r < KSEL; ++r) {
                u64 best = 0;
                for (int c = lane; c < ROWLEN; c += 64) {
                    u64 K = ((u64)f2u_sortable(rowp[c]) << 12) | (u64)(ROWLEN - 1 - c);
                    if (K < prev && K > best) best = K;
                }
                for (int off = 32; off > 0; off >>= 1) {
                    u64 o = __shfl_xor(best, off, 64);
                    best = best > o ? best : o;
                }
                if (lane == 0) orow[r] = (ROWLEN - 1) - (int)(best & 0xFFFu);
                prev = best;
            }
        }
    }
}

extern "C" void kernel_launch(void* const* d_in, const int* in_sizes, int n_in,
                              void* d_out, int out_size, void* d_ws, size_t ws_size,
                              hipStream_t stream) {
    const float* in = (const float*)d_in[0];
    const int B = in_sizes[0] / (ROWLEN * ROWLEN);   // 4
    const int nrows = B * ROWLEN;                    // 16384
    int* out = (int*)d_out;
    int* out_idx = out;                              // B*L*KSEL
    int* out_k   = out + (size_t)nrows * KSEL;       // B*L
    adaptive_topk_kernel<<<dim3(nrows), dim3(NTHREADS), 0, stream>>>(in, out_idx, out_k);
}